// Round 1
// baseline (66.365 us; speedup 1.0000x reference)
//
#include <hip/hip_runtime.h>

constexpr int NC = 16;        // n_cgs
constexpr int NP = 256;       // npair = NC*NC
constexpr int NPAD = 257;     // LDS pad
constexpr int NATOMS = 512;
constexpr int NB = 128;
constexpr int WROW = NP + NP * NP;  // 65792 floats per W row

// ---------------------------------------------------------------------------
// Kernel 1: per-atom-row contraction of W with the sparse basis maps.
//   H[d][q]   = sum_p W2[p][q] * (d==p&15 ? +1 : 0) + (d==p>>4 ? -1 : 0)
//   Wcd[c][d] = sum_q H[d][q] * (c==q&15 ? +1 : 0) + (c==q>>4 ? -1 : 0)
//   W1c[c]    = sum_p W1[p]   * (c==p&15 ? +1 : 0) + (c==p>>4 ? -1 : 0)
// Stored as wcd[n*256 + d*16 + c], w1c[n*16 + c].
// ---------------------------------------------------------------------------
__global__ __launch_bounds__(256) void k_reduceW(const float* __restrict__ W,
                                                 float* __restrict__ wcd,
                                                 float* __restrict__ w1c) {
    __shared__ float Hp[4][NC][NPAD];   // partial H per row-quarter
    const int n = blockIdx.x;
    const int t = threadIdx.x;
    const int rq = t >> 6;   // row quarter: rows [rq*64, rq*64+64)
    const int q4 = t & 63;   // column group: cols [4*q4, 4*q4+4)
    const float* __restrict__ Wrow = W + (size_t)n * WROW;
    const float* __restrict__ W2 = Wrow + NP;

    float h0[NC], h1[NC], h2[NC], h3[NC];   // +pj contributions per column
    float hn0[4], hn1[4], hn2[4], hn3[4];   // -pi contributions (pi = rq*4+k)
#pragma unroll
    for (int d = 0; d < NC; ++d) { h0[d] = 0.f; h1[d] = 0.f; h2[d] = 0.f; h3[d] = 0.f; }
#pragma unroll
    for (int k = 0; k < 4; ++k) { hn0[k] = 0.f; hn1[k] = 0.f; hn2[k] = 0.f; hn3[k] = 0.f; }

    // coalesced: each wave reads a contiguous 1KB row slice per iteration
    const float4* __restrict__ base = (const float4*)(W2 + (size_t)(rq * 64) * NP) + q4;
#pragma unroll
    for (int i = 0; i < 64; ++i) {
        float4 v = base[(size_t)i * 64];   // row rq*64+i, cols 4*q4..4*q4+3
        h0[i & 15] += v.x;  hn0[i >> 4] += v.x;
        h1[i & 15] += v.y;  hn1[i >> 4] += v.y;
        h2[i & 15] += v.z;  hn2[i >> 4] += v.z;
        h3[i & 15] += v.w;  hn3[i >> 4] += v.w;
    }
    // fold -pi part: h[rq*4+k] -= hn[k]  (branch keeps indices compile-time)
    switch (rq) {
      case 0:
#pragma unroll
        for (int k = 0; k < 4; ++k) { h0[k] -= hn0[k]; h1[k] -= hn1[k]; h2[k] -= hn2[k]; h3[k] -= hn3[k]; }
        break;
      case 1:
#pragma unroll
        for (int k = 0; k < 4; ++k) { h0[4+k] -= hn0[k]; h1[4+k] -= hn1[k]; h2[4+k] -= hn2[k]; h3[4+k] -= hn3[k]; }
        break;
      case 2:
#pragma unroll
        for (int k = 0; k < 4; ++k) { h0[8+k] -= hn0[k]; h1[8+k] -= hn1[k]; h2[8+k] -= hn2[k]; h3[8+k] -= hn3[k]; }
        break;
      default:
#pragma unroll
        for (int k = 0; k < 4; ++k) { h0[12+k] -= hn0[k]; h1[12+k] -= hn1[k]; h2[12+k] -= hn2[k]; h3[12+k] -= hn3[k]; }
        break;
    }
#pragma unroll
    for (int d = 0; d < NC; ++d) {
        Hp[rq][d][q4 * 4 + 0] = h0[d];
        Hp[rq][d][q4 * 4 + 1] = h1[d];
        Hp[rq][d][q4 * 4 + 2] = h2[d];
        Hp[rq][d][q4 * 4 + 3] = h3[d];
    }
    __syncthreads();

    // stage 2: thread t -> (d = t>>4, c = t&15); output index d*16+c == t (coalesced)
    {
        const int d = t >> 4, c = t & 15;
        float acc = 0.f;
#pragma unroll
        for (int qi = 0; qi < NC; ++qi) {
            const int q = qi * NC + c;
            acc += Hp[0][d][q] + Hp[1][d][q] + Hp[2][d][q] + Hp[3][d][q];
        }
#pragma unroll
        for (int qj = 0; qj < NC; ++qj) {
            const int q = c * NC + qj;
            acc -= Hp[0][d][q] + Hp[1][d][q] + Hp[2][d][q] + Hp[3][d][q];
        }
        wcd[n * NP + t] = acc;
    }
    if (t < NC) {
        const int c = t;
        float acc = 0.f;
#pragma unroll
        for (int pi = 0; pi < NC; ++pi) acc += Wrow[pi * NC + c];
#pragma unroll
        for (int pj = 0; pj < NC; ++pj) acc -= Wrow[c * NC + pj];
        w1c[n * NC + c] = acc;
    }
}

// ---------------------------------------------------------------------------
// Kernel 2: per-batch reconstruction.
//   dx[n]      = sum_m wcd[n][m] * (x[m&15] cross x[m>>4]) + sum_c w1c[n][c]*x[c]
//   cgo[j]     = sum_i an[i][j] * dx[i]
//   recon[n]   = x[idx[n]] - cgo[idx[n]] + dx[n]
// ---------------------------------------------------------------------------
__global__ __launch_bounds__(512) void k_recon(const float* __restrict__ cg_xyz,
                                               const float* __restrict__ assign_norm,
                                               const int* __restrict__ assign_idx,
                                               const float* __restrict__ wcd,
                                               const float* __restrict__ w1c,
                                               float* __restrict__ out_recon) {
    __shared__ float xs[NC][4];
    __shared__ float cxs[NP][4];
    __shared__ float part[8][48];
    __shared__ float cgo[48];
    const int b = blockIdx.x;
    const int t = threadIdx.x;

    if (t < NC * 3) xs[t / 3][t % 3] = cg_xyz[(size_t)b * NC * 3 + t];
    __syncthreads();
    if (t < NP) {
        const int c = t & 15, d = t >> 4;
        const float ax = xs[c][0], ay = xs[c][1], az = xs[c][2];
        const float bx = xs[d][0], by = xs[d][1], bz = xs[d][2];
        cxs[t][0] = ay * bz - az * by;
        cxs[t][1] = az * bx - ax * bz;
        cxs[t][2] = ax * by - ay * bx;
        cxs[t][3] = 0.f;
    }
    __syncthreads();

    const int n = t;  // one atom per thread
    float dx0 = 0.f, dx1 = 0.f, dx2 = 0.f;
    const float4* __restrict__ wrow = (const float4*)(wcd + n * NP);
#pragma unroll 8
    for (int k4 = 0; k4 < 64; ++k4) {
        const float4 w = wrow[k4];
        const float4 c0 = *(const float4*)(&cxs[k4 * 4 + 0][0]);
        const float4 c1 = *(const float4*)(&cxs[k4 * 4 + 1][0]);
        const float4 c2 = *(const float4*)(&cxs[k4 * 4 + 2][0]);
        const float4 c3 = *(const float4*)(&cxs[k4 * 4 + 3][0]);
        dx0 += w.x * c0.x + w.y * c1.x + w.z * c2.x + w.w * c3.x;
        dx1 += w.x * c0.y + w.y * c1.y + w.z * c2.y + w.w * c3.y;
        dx2 += w.x * c0.z + w.y * c1.z + w.z * c2.z + w.w * c3.z;
    }
    const float* __restrict__ w1row = w1c + n * NC;
#pragma unroll
    for (int c = 0; c < NC; ++c) {
        const float wv = w1row[c];
        dx0 += wv * xs[c][0]; dx1 += wv * xs[c][1]; dx2 += wv * xs[c][2];
    }

    // cg_offset: per-wave butterfly reduction over atoms, then LDS combine
    float an[NC];
    const float4* __restrict__ anr =
        (const float4*)(assign_norm + ((size_t)b * NATOMS + n) * NC);
#pragma unroll
    for (int i = 0; i < 4; ++i) {
        const float4 v = anr[i];
        an[4 * i + 0] = v.x; an[4 * i + 1] = v.y; an[4 * i + 2] = v.z; an[4 * i + 3] = v.w;
    }
    const int wv_ = t >> 6;
#pragma unroll
    for (int j = 0; j < NC; ++j) {
        float p0 = an[j] * dx0, p1 = an[j] * dx1, p2 = an[j] * dx2;
#pragma unroll
        for (int s = 1; s < 64; s <<= 1) {
            p0 += __shfl_xor(p0, s);
            p1 += __shfl_xor(p1, s);
            p2 += __shfl_xor(p2, s);
        }
        if ((t & 63) == 0) {
            part[wv_][j * 3 + 0] = p0;
            part[wv_][j * 3 + 1] = p1;
            part[wv_][j * 3 + 2] = p2;
        }
    }
    __syncthreads();
    if (t < 48) {
        float s = 0.f;
#pragma unroll
        for (int w8 = 0; w8 < 8; ++w8) s += part[w8][t];
        cgo[t] = s;
    }
    __syncthreads();

    const int ci = assign_idx[n];
    const float r0 = xs[ci][0] - cgo[ci * 3 + 0] + dx0;
    const float r1 = xs[ci][1] - cgo[ci * 3 + 1] + dx1;
    const float r2 = xs[ci][2] - cgo[ci * 3 + 2] + dx2;
    const size_t ob = ((size_t)b * NATOMS + n) * 3;
    out_recon[ob + 0] = r0;
    out_recon[ob + 1] = r1;
    out_recon[ob + 2] = r2;
}

extern "C" void kernel_launch(void* const* d_in, const int* in_sizes, int n_in,
                              void* d_out, int out_size, void* d_ws, size_t ws_size,
                              hipStream_t stream) {
    (void)in_sizes; (void)n_in; (void)out_size; (void)ws_size;
    const float* soft_assign = (const float*)d_in[0];
    const float* xyz         = (const float*)d_in[1];
    const float* cg_xyz      = (const float*)d_in[2];
    const float* assign_norm = (const float*)d_in[3];
    const float* W           = (const float*)d_in[4];
    const int*   assign_idx  = (const int*)d_in[5];

    float* out       = (float*)d_out;
    float* out_sa    = out;                                   // 128*512*16
    float* out_xyz   = out + (size_t)NB * NATOMS * NC;        // 128*512*3
    float* out_recon = out_xyz + (size_t)NB * NATOMS * 3;

    float* wcd = (float*)d_ws;                                // 512*256 floats
    float* w1c = wcd + (size_t)NATOMS * NP;                   // 512*16 floats

    hipMemcpyAsync(out_sa, soft_assign, (size_t)NB * NATOMS * NC * sizeof(float),
                   hipMemcpyDeviceToDevice, stream);
    hipMemcpyAsync(out_xyz, xyz, (size_t)NB * NATOMS * 3 * sizeof(float),
                   hipMemcpyDeviceToDevice, stream);

    k_reduceW<<<dim3(NATOMS), dim3(256), 0, stream>>>(W, wcd, w1c);
    k_recon<<<dim3(NB), dim3(512), 0, stream>>>(cg_xyz, assign_norm, assign_idx,
                                                wcd, w1c, out_recon);
}

// Round 2
// 58.434 us; speedup vs baseline: 1.1357x; 1.1357x over previous
//
#include <hip/hip_runtime.h>

constexpr int NC = 16;        // n_cgs
constexpr int NP = 256;       // npair = NC*NC
constexpr int NPAD = 264;     // LDS pitch (floats): 264%32=8 -> <=2-way conflicts on fold
constexpr int NATOMS = 512;
constexpr int NB = 128;
constexpr int WROW = NP + NP * NP;  // 65792 floats per W row

// ---------------------------------------------------------------------------
// Kernel 1: per-(atom, row-chunk) contraction of W2 with the sparse basis maps.
//   grid = 512 atoms x 4 chunks of 64 rows. Each thread reads 16 consecutive
//   rows (p&15 == i exactly once each; p>>4 fixed) x 4 columns.
//   H[d][q] = sum_p W2[p][q] * (delta(d,p&15) - delta(d,p>>4))
//   Wcd[c][d] += sum_q H[d][q] * (delta(c,q&15) - delta(c,q>>4))   (atomicAdd)
//   d-fold done in two halves so LDS = 4*8*264*4 = 33 KB -> 4 blocks/CU.
// Layout: wcd[n*256 + d*16 + c], w1c[n*16 + c].
// ---------------------------------------------------------------------------
__global__ __launch_bounds__(256) void k_reduceW(const float* __restrict__ W,
                                                 float* __restrict__ wcd,
                                                 float* __restrict__ w1c) {
    __shared__ float Hp[4][8][NPAD];
    const int bid = blockIdx.x;
    const int n = bid >> 2;
    const int chunk = bid & 3;
    const int t = threadIdx.x;
    const int s = t >> 6;    // sub-chunk: rows [chunk*64 + s*16, +16)
    const int q4 = t & 63;   // cols [4*q4, 4*q4+4)
    const float* __restrict__ Wrow = W + (size_t)n * WROW;
    const float* __restrict__ W2 = Wrow + NP;
    const int r0 = chunk * 64 + s * 16;
    const int pfix = r0 >> 4;            // == p>>4 for all 16 rows

    float h0[NC], h1[NC], h2[NC], h3[NC];
    float hn0 = 0.f, hn1 = 0.f, hn2 = 0.f, hn3 = 0.f;
    const float4* __restrict__ base = (const float4*)(W2 + (size_t)r0 * NP) + q4;
#pragma unroll
    for (int i = 0; i < 16; ++i) {
        float4 v = base[(size_t)i * 64];   // row r0+i, cols 4*q4..4*q4+3
        h0[i] = v.x; h1[i] = v.y; h2[i] = v.z; h3[i] = v.w;  // p&15 == i
        hn0 += v.x; hn1 += v.y; hn2 += v.z; hn3 += v.w;      // p>>4 == pfix
    }

    // ---- phase A: d in [0,8) ----
#pragma unroll
    for (int d = 0; d < 8; ++d) {
        float4 w;
        w.x = h0[d] - (d == pfix ? hn0 : 0.f);
        w.y = h1[d] - (d == pfix ? hn1 : 0.f);
        w.z = h2[d] - (d == pfix ? hn2 : 0.f);
        w.w = h3[d] - (d == pfix ? hn3 : 0.f);
        *(float4*)(&Hp[s][d][q4 * 4]) = w;   // contiguous per wave: conflict-free
    }
    __syncthreads();
    if (t < 128) {
        const int d = t >> 4, c = t & 15;
        float acc = 0.f;
#pragma unroll
        for (int qi = 0; qi < NC; ++qi) {
            const int q = qi * NC + c;
            acc += Hp[0][d][q] + Hp[1][d][q] + Hp[2][d][q] + Hp[3][d][q];
        }
#pragma unroll
        for (int qj = 0; qj < NC; ++qj) {
            const int q = c * NC + qj;
            acc -= Hp[0][d][q] + Hp[1][d][q] + Hp[2][d][q] + Hp[3][d][q];
        }
        atomicAdd(&wcd[n * NP + d * NC + c], acc);
    }
    __syncthreads();

    // ---- phase B: d in [8,16) ----
#pragma unroll
    for (int d = 8; d < 16; ++d) {
        float4 w;
        w.x = h0[d] - (d == pfix ? hn0 : 0.f);
        w.y = h1[d] - (d == pfix ? hn1 : 0.f);
        w.z = h2[d] - (d == pfix ? hn2 : 0.f);
        w.w = h3[d] - (d == pfix ? hn3 : 0.f);
        *(float4*)(&Hp[s][d - 8][q4 * 4]) = w;
    }
    __syncthreads();
    if (t < 128) {
        const int d = (t >> 4) + 8, c = t & 15;
        const int dd = d - 8;
        float acc = 0.f;
#pragma unroll
        for (int qi = 0; qi < NC; ++qi) {
            const int q = qi * NC + c;
            acc += Hp[0][dd][q] + Hp[1][dd][q] + Hp[2][dd][q] + Hp[3][dd][q];
        }
#pragma unroll
        for (int qj = 0; qj < NC; ++qj) {
            const int q = c * NC + qj;
            acc -= Hp[0][dd][q] + Hp[1][dd][q] + Hp[2][dd][q] + Hp[3][dd][q];
        }
        atomicAdd(&wcd[n * NP + d * NC + c], acc);
    }

    // W1 part: only chunk-0 blocks, 16 threads
    if (chunk == 0 && t < NC) {
        const int c = t;
        float acc = 0.f;
#pragma unroll
        for (int pi = 0; pi < NC; ++pi) acc += Wrow[pi * NC + c];
#pragma unroll
        for (int pj = 0; pj < NC; ++pj) acc -= Wrow[c * NC + pj];
        w1c[n * NC + c] = acc;
    }
}

// ---------------------------------------------------------------------------
// Kernel 2: dx + partial cg_offset.  grid = 128 batches x 2 atom-halves.
// ---------------------------------------------------------------------------
__global__ __launch_bounds__(256) void k_dx(const float* __restrict__ cg_xyz,
                                            const float* __restrict__ assign_norm,
                                            const float* __restrict__ wcd,
                                            const float* __restrict__ w1c,
                                            float* __restrict__ dx_g,
                                            float* __restrict__ cgo_g) {
    __shared__ float xs[NC][4];
    __shared__ float cxs[NP][4];
    __shared__ float part[4][48];
    const int b = blockIdx.x >> 1;
    const int h = blockIdx.x & 1;
    const int t = threadIdx.x;

    if (t < NC * 3) xs[t / 3][t % 3] = cg_xyz[(size_t)b * NC * 3 + t];
    __syncthreads();
    {
        const int c = t & 15, d = t >> 4;
        const float ax = xs[c][0], ay = xs[c][1], az = xs[c][2];
        const float bx = xs[d][0], by = xs[d][1], bz = xs[d][2];
        cxs[t][0] = ay * bz - az * by;
        cxs[t][1] = az * bx - ax * bz;
        cxs[t][2] = ax * by - ay * bx;
        cxs[t][3] = 0.f;
    }
    __syncthreads();

    const int n = h * 256 + t;           // atom index within batch
    float dx0 = 0.f, dx1 = 0.f, dx2 = 0.f;
    const float4* __restrict__ wrow = (const float4*)(wcd + n * NP);
#pragma unroll 8
    for (int k4 = 0; k4 < 64; ++k4) {
        const float4 w = wrow[k4];
        const float4 c0 = *(const float4*)(&cxs[k4 * 4 + 0][0]);
        const float4 c1 = *(const float4*)(&cxs[k4 * 4 + 1][0]);
        const float4 c2 = *(const float4*)(&cxs[k4 * 4 + 2][0]);
        const float4 c3 = *(const float4*)(&cxs[k4 * 4 + 3][0]);
        dx0 += w.x * c0.x + w.y * c1.x + w.z * c2.x + w.w * c3.x;
        dx1 += w.x * c0.y + w.y * c1.y + w.z * c2.y + w.w * c3.y;
        dx2 += w.x * c0.z + w.y * c1.z + w.z * c2.z + w.w * c3.z;
    }
    const float* __restrict__ w1row = w1c + n * NC;
#pragma unroll
    for (int c = 0; c < NC; ++c) {
        const float wv = w1row[c];
        dx0 += wv * xs[c][0]; dx1 += wv * xs[c][1]; dx2 += wv * xs[c][2];
    }

    float an[NC];
    const float4* __restrict__ anr =
        (const float4*)(assign_norm + ((size_t)b * NATOMS + n) * NC);
#pragma unroll
    for (int i = 0; i < 4; ++i) {
        const float4 v = anr[i];
        an[4 * i + 0] = v.x; an[4 * i + 1] = v.y; an[4 * i + 2] = v.z; an[4 * i + 3] = v.w;
    }
    const int wv_ = t >> 6;
#pragma unroll
    for (int j = 0; j < NC; ++j) {
        float p0 = an[j] * dx0, p1 = an[j] * dx1, p2 = an[j] * dx2;
#pragma unroll
        for (int s = 1; s < 64; s <<= 1) {
            p0 += __shfl_xor(p0, s);
            p1 += __shfl_xor(p1, s);
            p2 += __shfl_xor(p2, s);
        }
        if ((t & 63) == 0) {
            part[wv_][j * 3 + 0] = p0;
            part[wv_][j * 3 + 1] = p1;
            part[wv_][j * 3 + 2] = p2;
        }
    }
    __syncthreads();
    if (t < 48) {
        atomicAdd(&cgo_g[b * 48 + t],
                  part[0][t] + part[1][t] + part[2][t] + part[3][t]);
    }

    const size_t ob = ((size_t)b * NATOMS + n) * 3;
    dx_g[ob + 0] = dx0;
    dx_g[ob + 1] = dx1;
    dx_g[ob + 2] = dx2;
}

// ---------------------------------------------------------------------------
// Kernel 3: recon[n] = cg[idx[n]] - cgo[idx[n]] + dx[n]
// ---------------------------------------------------------------------------
__global__ __launch_bounds__(256) void k_finish(const float* __restrict__ cg_xyz,
                                                const int* __restrict__ assign_idx,
                                                const float* __restrict__ dx_g,
                                                const float* __restrict__ cgo_g,
                                                float* __restrict__ out_recon) {
    const int idx = blockIdx.x * 256 + threadIdx.x;   // 0 .. 128*512-1
    const int b = idx >> 9;
    const int n = idx & 511;
    const int ci = assign_idx[n];
    const float* xsp = cg_xyz + (size_t)b * NC * 3 + ci * 3;
    const float* cgp = cgo_g + b * 48 + ci * 3;
    const float* dxp = dx_g + (size_t)idx * 3;
    float* op = out_recon + (size_t)idx * 3;
    op[0] = xsp[0] - cgp[0] + dxp[0];
    op[1] = xsp[1] - cgp[1] + dxp[1];
    op[2] = xsp[2] - cgp[2] + dxp[2];
}

extern "C" void kernel_launch(void* const* d_in, const int* in_sizes, int n_in,
                              void* d_out, int out_size, void* d_ws, size_t ws_size,
                              hipStream_t stream) {
    (void)in_sizes; (void)n_in; (void)out_size; (void)ws_size;
    const float* soft_assign = (const float*)d_in[0];
    const float* xyz         = (const float*)d_in[1];
    const float* cg_xyz      = (const float*)d_in[2];
    const float* assign_norm = (const float*)d_in[3];
    const float* W           = (const float*)d_in[4];
    const int*   assign_idx  = (const int*)d_in[5];

    float* out       = (float*)d_out;
    float* out_sa    = out;                                   // 128*512*16
    float* out_xyz   = out + (size_t)NB * NATOMS * NC;        // 128*512*3
    float* out_recon = out_xyz + (size_t)NB * NATOMS * 3;

    float* wcd   = (float*)d_ws;                              // 512*256
    float* w1c   = wcd + (size_t)NATOMS * NP;                 // 512*16
    float* dx_g  = w1c + (size_t)NATOMS * NC;                 // 128*512*3
    float* cgo_g = dx_g + (size_t)NB * NATOMS * 3;            // 128*48

    hipMemsetAsync(wcd, 0, (size_t)NATOMS * NP * sizeof(float), stream);
    hipMemsetAsync(cgo_g, 0, (size_t)NB * 48 * sizeof(float), stream);

    hipMemcpyAsync(out_sa, soft_assign, (size_t)NB * NATOMS * NC * sizeof(float),
                   hipMemcpyDeviceToDevice, stream);
    hipMemcpyAsync(out_xyz, xyz, (size_t)NB * NATOMS * 3 * sizeof(float),
                   hipMemcpyDeviceToDevice, stream);

    k_reduceW<<<dim3(NATOMS * 4), dim3(256), 0, stream>>>(W, wcd, w1c);
    k_dx<<<dim3(NB * 2), dim3(256), 0, stream>>>(cg_xyz, assign_norm, wcd, w1c,
                                                 dx_g, cgo_g);
    k_finish<<<dim3(NB * 2), dim3(256), 0, stream>>>(cg_xyz, assign_idx, dx_g,
                                                     cgo_g, out_recon);
}

// Round 3
// 54.837 us; speedup vs baseline: 1.2102x; 1.0656x over previous
//
#include <hip/hip_runtime.h>

constexpr int NC = 16;        // n_cgs
constexpr int NP = 256;       // npair = NC*NC
constexpr int NPAD = 264;     // LDS pitch (floats): 264%32=8 -> <=2-way conflicts on fold
constexpr int NATOMS = 512;
constexpr int NB = 128;
constexpr int WROW = NP + NP * NP;  // 65792 floats per W row

// ---------------------------------------------------------------------------
// Kernel 1: per-(atom, row-chunk) contraction of W2 with the sparse basis maps.
//   grid = 512 atoms x 4 chunks of 64 rows. Each thread reads 16 consecutive
//   rows (p&15 == i exactly once each; p>>4 fixed) x 4 columns.
//   H[d][q] = sum_p W2[p][q] * (delta(d,p&15) - delta(d,p>>4))
//   partial Wcd[c][d] = sum_q H[d][q] * (delta(c,q&15) - delta(c,q>>4))
//   -> wcd_part[chunk][n][d*16+c]   (plain stores, no atomics)
// Also copies soft_assign and xyz into the output buffer (absorbs 2 graph
// nodes into an already HBM-bound stream).
// ---------------------------------------------------------------------------
__global__ __launch_bounds__(256) void k_reduceW(const float* __restrict__ W,
                                                 const float* __restrict__ soft_assign,
                                                 const float* __restrict__ xyz,
                                                 float* __restrict__ wcd_part,
                                                 float* __restrict__ w1c,
                                                 float* __restrict__ out_sa,
                                                 float* __restrict__ out_xyz) {
    __shared__ float Hp[4][8][NPAD];
    const int bid = blockIdx.x;
    const int n = bid >> 2;
    const int chunk = bid & 3;
    const int t = threadIdx.x;
    const int s = t >> 6;    // sub-chunk: rows [chunk*64 + s*16, +16)
    const int q4 = t & 63;   // cols [4*q4, 4*q4+4)
    const float* __restrict__ Wrow = W + (size_t)n * WROW;
    const float* __restrict__ W2 = Wrow + NP;
    const int r0 = chunk * 64 + s * 16;
    const int pfix = r0 >> 4;            // == p>>4 for all 16 rows

    // ---- absorbed output copies (issue loads early; overlap with W stream) ----
    {
        const float4* __restrict__ sa4 = (const float4*)soft_assign;
        float4* __restrict__ osa4 = (float4*)out_sa;
        if (t < 128) {
            const int ci = bid * 128 + t;      // 2048*128 = 262144 = full sa
            osa4[ci] = sa4[ci];
        } else if (t < 152) {
            const float4* __restrict__ x4 = (const float4*)xyz;
            float4* __restrict__ ox4 = (float4*)out_xyz;
            const int xi = bid * 24 + (t - 128);  // 2048*24 = 49152 = full xyz
            ox4[xi] = x4[xi];
        }
    }

    float h0[NC], h1[NC], h2[NC], h3[NC];
    float hn0 = 0.f, hn1 = 0.f, hn2 = 0.f, hn3 = 0.f;
    const float4* __restrict__ base = (const float4*)(W2 + (size_t)r0 * NP) + q4;
#pragma unroll
    for (int i = 0; i < 16; ++i) {
        float4 v = base[(size_t)i * 64];   // row r0+i, cols 4*q4..4*q4+3
        h0[i] = v.x; h1[i] = v.y; h2[i] = v.z; h3[i] = v.w;  // p&15 == i
        hn0 += v.x; hn1 += v.y; hn2 += v.z; hn3 += v.w;      // p>>4 == pfix
    }

    // ---- phase A: d in [0,8) ----
#pragma unroll
    for (int d = 0; d < 8; ++d) {
        float4 w;
        w.x = h0[d] - (d == pfix ? hn0 : 0.f);
        w.y = h1[d] - (d == pfix ? hn1 : 0.f);
        w.z = h2[d] - (d == pfix ? hn2 : 0.f);
        w.w = h3[d] - (d == pfix ? hn3 : 0.f);
        *(float4*)(&Hp[s][d][q4 * 4]) = w;   // contiguous per wave: conflict-free
    }
    __syncthreads();
    if (t < 128) {
        const int d = t >> 4, c = t & 15;
        float acc = 0.f;
#pragma unroll
        for (int qi = 0; qi < NC; ++qi) {
            const int q = qi * NC + c;
            acc += Hp[0][d][q] + Hp[1][d][q] + Hp[2][d][q] + Hp[3][d][q];
        }
#pragma unroll
        for (int qj = 0; qj < NC; ++qj) {
            const int q = c * NC + qj;
            acc -= Hp[0][d][q] + Hp[1][d][q] + Hp[2][d][q] + Hp[3][d][q];
        }
        wcd_part[((size_t)chunk * NATOMS + n) * NP + t] = acc;   // t == d*16+c
    }
    __syncthreads();

    // ---- phase B: d in [8,16) ----
#pragma unroll
    for (int d = 8; d < 16; ++d) {
        float4 w;
        w.x = h0[d] - (d == pfix ? hn0 : 0.f);
        w.y = h1[d] - (d == pfix ? hn1 : 0.f);
        w.z = h2[d] - (d == pfix ? hn2 : 0.f);
        w.w = h3[d] - (d == pfix ? hn3 : 0.f);
        *(float4*)(&Hp[s][d - 8][q4 * 4]) = w;
    }
    __syncthreads();
    if (t < 128) {
        const int dd = t >> 4, c = t & 15;
        float acc = 0.f;
#pragma unroll
        for (int qi = 0; qi < NC; ++qi) {
            const int q = qi * NC + c;
            acc += Hp[0][dd][q] + Hp[1][dd][q] + Hp[2][dd][q] + Hp[3][dd][q];
        }
#pragma unroll
        for (int qj = 0; qj < NC; ++qj) {
            const int q = c * NC + qj;
            acc -= Hp[0][dd][q] + Hp[1][dd][q] + Hp[2][dd][q] + Hp[3][dd][q];
        }
        wcd_part[((size_t)chunk * NATOMS + n) * NP + 128 + t] = acc;
    }

    // W1 part: only chunk-0 blocks, 16 threads
    if (chunk == 0 && t < NC) {
        const int c = t;
        float acc = 0.f;
#pragma unroll
        for (int pi = 0; pi < NC; ++pi) acc += Wrow[pi * NC + c];
#pragma unroll
        for (int pj = 0; pj < NC; ++pj) acc -= Wrow[c * NC + pj];
        w1c[n * NC + c] = acc;
    }
}

// ---------------------------------------------------------------------------
// Kernel 2: wcd = sum over 4 chunk partials.  32768 float4 total.
// ---------------------------------------------------------------------------
__global__ __launch_bounds__(256) void k_sumW(const float* __restrict__ wcd_part,
                                              float* __restrict__ wcd) {
    const int idx = blockIdx.x * 256 + threadIdx.x;   // 0 .. 32767
    const float4* __restrict__ p0 = (const float4*)wcd_part;
    const float4* __restrict__ p1 = p0 + (size_t)NATOMS * NP / 4;
    const float4* __restrict__ p2 = p1 + (size_t)NATOMS * NP / 4;
    const float4* __restrict__ p3 = p2 + (size_t)NATOMS * NP / 4;
    const float4 a = p0[idx], b = p1[idx], c = p2[idx], d = p3[idx];
    float4 r;
    r.x = (a.x + b.x) + (c.x + d.x);
    r.y = (a.y + b.y) + (c.y + d.y);
    r.z = (a.z + b.z) + (c.z + d.z);
    r.w = (a.w + b.w) + (c.w + d.w);
    ((float4*)wcd)[idx] = r;
}

// ---------------------------------------------------------------------------
// Kernel 3: per-batch reconstruction (one 512-thread block per batch).
//   dx[n]    = sum_m wcd[n][m] * (x[m&15] cross x[m>>4]) + sum_c w1c[n][c]*x[c]
//   cgo[j]   = sum_i an[i][j] * dx[i]           (in-block reduction)
//   recon[n] = x[idx[n]] - cgo[idx[n]] + dx[n]
// ---------------------------------------------------------------------------
__global__ __launch_bounds__(512) void k_recon(const float* __restrict__ cg_xyz,
                                               const float* __restrict__ assign_norm,
                                               const int* __restrict__ assign_idx,
                                               const float* __restrict__ wcd,
                                               const float* __restrict__ w1c,
                                               float* __restrict__ out_recon) {
    __shared__ float xs[NC][4];
    __shared__ float cxs[NP][4];
    __shared__ float part[8][48];
    __shared__ float cgo[48];
    const int b = blockIdx.x;
    const int t = threadIdx.x;

    if (t < NC * 3) xs[t / 3][t % 3] = cg_xyz[(size_t)b * NC * 3 + t];
    __syncthreads();
    if (t < NP) {
        const int c = t & 15, d = t >> 4;
        const float ax = xs[c][0], ay = xs[c][1], az = xs[c][2];
        const float bx = xs[d][0], by = xs[d][1], bz = xs[d][2];
        cxs[t][0] = ay * bz - az * by;
        cxs[t][1] = az * bx - ax * bz;
        cxs[t][2] = ax * by - ay * bx;
        cxs[t][3] = 0.f;
    }
    __syncthreads();

    const int n = t;  // one atom per thread
    float dx0 = 0.f, dx1 = 0.f, dx2 = 0.f;
    const float4* __restrict__ wrow = (const float4*)(wcd + n * NP);
#pragma unroll 8
    for (int k4 = 0; k4 < 64; ++k4) {
        const float4 w = wrow[k4];
        const float4 c0 = *(const float4*)(&cxs[k4 * 4 + 0][0]);
        const float4 c1 = *(const float4*)(&cxs[k4 * 4 + 1][0]);
        const float4 c2 = *(const float4*)(&cxs[k4 * 4 + 2][0]);
        const float4 c3 = *(const float4*)(&cxs[k4 * 4 + 3][0]);
        dx0 += w.x * c0.x + w.y * c1.x + w.z * c2.x + w.w * c3.x;
        dx1 += w.x * c0.y + w.y * c1.y + w.z * c2.y + w.w * c3.y;
        dx2 += w.x * c0.z + w.y * c1.z + w.z * c2.z + w.w * c3.z;
    }
    const float* __restrict__ w1row = w1c + n * NC;
#pragma unroll
    for (int c = 0; c < NC; ++c) {
        const float wv = w1row[c];
        dx0 += wv * xs[c][0]; dx1 += wv * xs[c][1]; dx2 += wv * xs[c][2];
    }

    // cg_offset: per-wave butterfly reduction over atoms, then LDS combine
    float an[NC];
    const float4* __restrict__ anr =
        (const float4*)(assign_norm + ((size_t)b * NATOMS + n) * NC);
#pragma unroll
    for (int i = 0; i < 4; ++i) {
        const float4 v = anr[i];
        an[4 * i + 0] = v.x; an[4 * i + 1] = v.y; an[4 * i + 2] = v.z; an[4 * i + 3] = v.w;
    }
    const int wv_ = t >> 6;
#pragma unroll
    for (int j = 0; j < NC; ++j) {
        float p0 = an[j] * dx0, p1 = an[j] * dx1, p2 = an[j] * dx2;
#pragma unroll
        for (int s = 1; s < 64; s <<= 1) {
            p0 += __shfl_xor(p0, s);
            p1 += __shfl_xor(p1, s);
            p2 += __shfl_xor(p2, s);
        }
        if ((t & 63) == 0) {
            part[wv_][j * 3 + 0] = p0;
            part[wv_][j * 3 + 1] = p1;
            part[wv_][j * 3 + 2] = p2;
        }
    }
    __syncthreads();
    if (t < 48) {
        float s = 0.f;
#pragma unroll
        for (int w8 = 0; w8 < 8; ++w8) s += part[w8][t];
        cgo[t] = s;
    }
    __syncthreads();

    const int ci = assign_idx[n];
    const float r0 = xs[ci][0] - cgo[ci * 3 + 0] + dx0;
    const float r1 = xs[ci][1] - cgo[ci * 3 + 1] + dx1;
    const float r2 = xs[ci][2] - cgo[ci * 3 + 2] + dx2;
    const size_t ob = ((size_t)b * NATOMS + n) * 3;
    out_recon[ob + 0] = r0;
    out_recon[ob + 1] = r1;
    out_recon[ob + 2] = r2;
}

extern "C" void kernel_launch(void* const* d_in, const int* in_sizes, int n_in,
                              void* d_out, int out_size, void* d_ws, size_t ws_size,
                              hipStream_t stream) {
    (void)in_sizes; (void)n_in; (void)out_size; (void)ws_size;
    const float* soft_assign = (const float*)d_in[0];
    const float* xyz         = (const float*)d_in[1];
    const float* cg_xyz      = (const float*)d_in[2];
    const float* assign_norm = (const float*)d_in[3];
    const float* W           = (const float*)d_in[4];
    const int*   assign_idx  = (const int*)d_in[5];

    float* out       = (float*)d_out;
    float* out_sa    = out;                                   // 128*512*16
    float* out_xyz   = out + (size_t)NB * NATOMS * NC;        // 128*512*3
    float* out_recon = out_xyz + (size_t)NB * NATOMS * 3;

    float* wcd_part = (float*)d_ws;                           // 4*512*256
    float* wcd      = wcd_part + (size_t)4 * NATOMS * NP;     // 512*256
    float* w1c      = wcd + (size_t)NATOMS * NP;              // 512*16

    k_reduceW<<<dim3(NATOMS * 4), dim3(256), 0, stream>>>(W, soft_assign, xyz,
                                                          wcd_part, w1c,
                                                          out_sa, out_xyz);
    k_sumW<<<dim3(NATOMS * NP / 4 / 256), dim3(256), 0, stream>>>(wcd_part, wcd);
    k_recon<<<dim3(NB), dim3(512), 0, stream>>>(cg_xyz, assign_norm, assign_idx,
                                                wcd, w1c, out_recon);
}